// Round 5
// baseline (231.370 us; speedup 1.0000x reference)
//
#include <hip/hip_runtime.h>

// VectorQuantizer: latents (16,128,64,64) f32, codebook (1024,128) f32.
// out[b,d,h,w] = codebook[argmin_k fl(fl(x2 - 2*dot(x,e_k)) + e2_k)][d]
//
// Single-sweep MFMA bf16 scoring + exact fp32 rescue:
//  pre-pass: 4 c-iters (256 codes) -> per-px upper bound ub on min s',
//            s' = e2 - 2*dot_bf (x2 dropped: constant per px).
//            thr = ub + 2M; M = 2e-4*sqrt(x2)+1.5e-4 bounds
//            |s'(k) - (t3(k)-x2)| (Cauchy-Schwarz on bf16 quantization,
//            e2max <= 128/1024^2, + fl-rounding slop). For true argmin k*:
//            s'(k*) <= s'(k0)+2M for all k0 => k* is always collected.
//  main:     16 c-iters with B[c+1] prefetch; collect {s' <= thr} into LDS;
//            track tight running min for an (essentially never taken)
//            overflow re-sweep fallback.
//  rescue:   exact fp32 serial ascending-d fmaf chain (round-1-validated),
//            lex (t3,k) u64 atomicMin -> np first-index tie-break (t3>0).
// Codebook streamed bf16 from L2 (never via SMEM - round-2 lesson).
// A-frags in 64 VGPRs; x-tile px-major in LDS (b128 A-build + rescue reads).

typedef __attribute__((ext_vector_type(8))) short short8;
typedef __attribute__((ext_vector_type(4))) float f32x4;

#define VQ_D 128
#define VQ_K 1024
#define VQ_HW 4096
#define ROWF 132          // padded x-row floats (16B-aligned rows)
#define CAND_CAP 3072

__device__ inline unsigned short f2bf(float f) {   // RNE fp32->bf16
    unsigned u = __float_as_uint(f);
    return (unsigned short)((u + 0x7FFFu + ((u >> 16) & 1u)) >> 16);
}

__global__ __launch_bounds__(128)
void vq_prep_kernel(const float* __restrict__ cb, unsigned short* __restrict__ cbbf,
                    float* __restrict__ e2) {
    const int k = blockIdx.x * 128 + threadIdx.x;
    const float* crow = cb + (size_t)k * VQ_D;
    unsigned short* brow = cbbf + (size_t)k * VQ_D;
    float s = 0.f;
    #pragma unroll
    for (int d = 0; d < VQ_D; ++d) {
        const float v = crow[d];
        s = fmaf(v, v, s);          // serial chain (rounds 1-4 validated)
        brow[d] = f2bf(v);
    }
    e2[k] = s;
}

__global__ __launch_bounds__(256, 3)
void vq_main_kernel(const float* __restrict__ latents,
                    const float* __restrict__ cb,
                    const unsigned short* __restrict__ cbbf,
                    const float* __restrict__ e2g,
                    float* __restrict__ out) {
    __shared__ __align__(16) float xl[64 * ROWF];   // px-major, 33792 B
    __shared__ float e2l[VQ_K];
    __shared__ unsigned int cand[CAND_CAP];
    __shared__ float pmins[4][64];
    __shared__ float threshs[64];
    __shared__ float x2s[64];
    __shared__ unsigned long long fkey[64];
    __shared__ int ncand;

    const int tid  = threadIdx.x;
    const int lane = tid & 63;
    const int wave = __builtin_amdgcn_readfirstlane(tid >> 6);
    const int quad = lane >> 4;
    const int mm   = lane & 15;
    const int blk  = blockIdx.x;
    const int b    = blk >> 6;
    const int hw0  = (blk & 63) << 6;

    const float* xg = latents + (size_t)b * VQ_D * VQ_HW + hw0;

    // ---- stage x-tile (px-major) + e2 ----
    {
        const int px4 = (tid & 15) << 2;
        const int d0  = (tid >> 4) << 3;
        #pragma unroll
        for (int i = 0; i < 8; ++i) {
            const int d = d0 + i;
            const float4 v = *(const float4*)(xg + (size_t)d * VQ_HW + px4);
            xl[(px4 + 0) * ROWF + d] = v.x;
            xl[(px4 + 1) * ROWF + d] = v.y;
            xl[(px4 + 2) * ROWF + d] = v.z;
            xl[(px4 + 3) * ROWF + d] = v.w;
        }
        #pragma unroll
        for (int r = 0; r < 4; ++r) e2l[r * 256 + tid] = e2g[r * 256 + tid];
    }
    if (tid == 0) ncand = 0;
    if (tid < 64) fkey[tid] = ~0ULL;
    __syncthreads();

    // ---- A fragments: px = p*16+mm, d = t*32+quad*8+j  (2 b128 each) ----
    short8 A[16];
    #pragma unroll
    for (int p = 0; p < 4; ++p) {
        #pragma unroll
        for (int t = 0; t < 4; ++t) {
            const float* xp = xl + (p * 16 + mm) * ROWF + t * 32 + quad * 8;
            const float4 f0 = *(const float4*)(xp);
            const float4 f1 = *(const float4*)(xp + 4);
            short8 a;
            a[0] = (short)f2bf(f0.x); a[1] = (short)f2bf(f0.y);
            a[2] = (short)f2bf(f0.z); a[3] = (short)f2bf(f0.w);
            a[4] = (short)f2bf(f1.x); a[5] = (short)f2bf(f1.y);
            a[6] = (short)f2bf(f1.z); a[7] = (short)f2bf(f1.w);
            A[p * 4 + t] = a;
        }
    }

    // ---- x2: serial ascending-d chain, from global (L1-hot), 1 thr/px ----
    float x2 = 0.f;
    if (tid < 64) {
        #pragma unroll
        for (int d = 0; d < VQ_D; ++d) {
            const float v = xg[(size_t)d * VQ_HW + tid];
            x2 = fmaf(v, v, x2);
        }
        x2s[tid] = x2;
    }

    const unsigned short* bbase =
        cbbf + (size_t)(wave * 256 + mm) * VQ_D + quad * 8;

    // ---- pre-pass: 4 c-iters -> per-px ub over 256 codes ----
    float bmin[16];
    #pragma unroll
    for (int i = 0; i < 16; ++i) bmin[i] = 1e30f;

    #pragma unroll 2
    for (int c = 0; c < 4; ++c) {
        short8 B[4];
        #pragma unroll
        for (int t = 0; t < 4; ++t)
            B[t] = *(const short8*)(bbase + (size_t)c * 16 * VQ_D + t * 32);
        f32x4 C[4] = {{0.f,0.f,0.f,0.f},{0.f,0.f,0.f,0.f},
                      {0.f,0.f,0.f,0.f},{0.f,0.f,0.f,0.f}};
        #pragma unroll
        for (int t = 0; t < 4; ++t)
            #pragma unroll
            for (int p = 0; p < 4; ++p)
                C[p] = __builtin_amdgcn_mfma_f32_16x16x32_bf16(
                           A[p * 4 + t], B[t], C[p], 0, 0, 0);
        const float e2c = e2l[wave * 256 + c * 16 + mm];
        #pragma unroll
        for (int p = 0; p < 4; ++p)
            #pragma unroll
            for (int r = 0; r < 4; ++r) {
                const float s = fmaf(-2.0f, C[p][r], e2c);
                bmin[p * 4 + r] = fminf(bmin[p * 4 + r], s);
            }
    }
    #pragma unroll
    for (int i = 0; i < 16; ++i) {
        float v = bmin[i];
        v = fminf(v, __shfl_xor(v, 1));
        v = fminf(v, __shfl_xor(v, 2));
        v = fminf(v, __shfl_xor(v, 4));
        v = fminf(v, __shfl_xor(v, 8));
        bmin[i] = v;
    }
    if (mm == 0) {
        #pragma unroll
        for (int p = 0; p < 4; ++p)
            #pragma unroll
            for (int r = 0; r < 4; ++r)
                pmins[wave][p * 16 + quad * 4 + r] = bmin[p * 4 + r];
    }
    __syncthreads();
    if (tid < 64) {
        const float ub = fminf(fminf(pmins[0][tid], pmins[1][tid]),
                               fminf(pmins[2][tid], pmins[3][tid]));
        const float M = 2.0e-4f * sqrtf(x2) + 1.5e-4f;
        threshs[tid] = ub + 2.0f * M;
    }
    __syncthreads();

    float thr[16];
    #pragma unroll
    for (int p = 0; p < 4; ++p)
        #pragma unroll
        for (int r = 0; r < 4; ++r)
            thr[p * 4 + r] = threshs[p * 16 + quad * 4 + r];

    // ---- main sweep: 16 c-iters, B prefetch, collect candidates ----
    float rmin[16];
    #pragma unroll
    for (int i = 0; i < 16; ++i) rmin[i] = 1e30f;

    short8 Bc[4], Bn[4];
    #pragma unroll
    for (int t = 0; t < 4; ++t)
        Bc[t] = *(const short8*)(bbase + (size_t)t * 32);

    #pragma unroll 1
    for (int c = 0; c < 16; ++c) {
        if (c < 15) {
            #pragma unroll
            for (int t = 0; t < 4; ++t)
                Bn[t] = *(const short8*)(bbase + (size_t)(c + 1) * 16 * VQ_D + t * 32);
        }
        f32x4 C[4] = {{0.f,0.f,0.f,0.f},{0.f,0.f,0.f,0.f},
                      {0.f,0.f,0.f,0.f},{0.f,0.f,0.f,0.f}};
        #pragma unroll
        for (int t = 0; t < 4; ++t)
            #pragma unroll
            for (int p = 0; p < 4; ++p)
                C[p] = __builtin_amdgcn_mfma_f32_16x16x32_bf16(
                           A[p * 4 + t], Bc[t], C[p], 0, 0, 0);
        const float e2c  = e2l[wave * 256 + c * 16 + mm];
        const int   code = wave * 256 + c * 16 + mm;
        #pragma unroll
        for (int p = 0; p < 4; ++p)
            #pragma unroll
            for (int r = 0; r < 4; ++r) {
                const float s = fmaf(-2.0f, C[p][r], e2c);
                rmin[p * 4 + r] = fminf(rmin[p * 4 + r], s);
                if (s <= thr[p * 4 + r]) {
                    const int idx = atomicAdd(&ncand, 1);
                    if (idx < CAND_CAP) {
                        const int px = p * 16 + quad * 4 + r;
                        cand[idx] = ((unsigned)px << 16) | (unsigned)code;
                    }
                }
            }
        #pragma unroll
        for (int t = 0; t < 4; ++t) Bc[t] = Bn[t];
    }
    __syncthreads();

    int nc = ncand;
    if (nc > CAND_CAP) {
        // Fallback (essentially never): tight threshold from exact running
        // min, re-collect. Guaranteed small candidate set.
        #pragma unroll
        for (int i = 0; i < 16; ++i) {
            float v = rmin[i];
            v = fminf(v, __shfl_xor(v, 1));
            v = fminf(v, __shfl_xor(v, 2));
            v = fminf(v, __shfl_xor(v, 4));
            v = fminf(v, __shfl_xor(v, 8));
            rmin[i] = v;
        }
        if (mm == 0) {
            #pragma unroll
            for (int p = 0; p < 4; ++p)
                #pragma unroll
                for (int r = 0; r < 4; ++r)
                    pmins[wave][p * 16 + quad * 4 + r] = rmin[p * 4 + r];
        }
        __syncthreads();
        if (tid == 0) ncand = 0;
        if (tid < 64) {
            const float mn = fminf(fminf(pmins[0][tid], pmins[1][tid]),
                                   fminf(pmins[2][tid], pmins[3][tid]));
            const float M = 2.0e-4f * sqrtf(x2) + 1.5e-4f;
            threshs[tid] = mn + 2.0f * M;
        }
        __syncthreads();
        #pragma unroll
        for (int p = 0; p < 4; ++p)
            #pragma unroll
            for (int r = 0; r < 4; ++r)
                thr[p * 4 + r] = threshs[p * 16 + quad * 4 + r];
        #pragma unroll 1
        for (int c = 0; c < 16; ++c) {
            short8 B[4];
            #pragma unroll
            for (int t = 0; t < 4; ++t)
                B[t] = *(const short8*)(bbase + (size_t)c * 16 * VQ_D + t * 32);
            f32x4 C[4] = {{0.f,0.f,0.f,0.f},{0.f,0.f,0.f,0.f},
                          {0.f,0.f,0.f,0.f},{0.f,0.f,0.f,0.f}};
            #pragma unroll
            for (int t = 0; t < 4; ++t)
                #pragma unroll
                for (int p = 0; p < 4; ++p)
                    C[p] = __builtin_amdgcn_mfma_f32_16x16x32_bf16(
                               A[p * 4 + t], B[t], C[p], 0, 0, 0);
            const float e2c  = e2l[wave * 256 + c * 16 + mm];
            const int   code = wave * 256 + c * 16 + mm;
            #pragma unroll
            for (int p = 0; p < 4; ++p)
                #pragma unroll
                for (int r = 0; r < 4; ++r) {
                    const float s = fmaf(-2.0f, C[p][r], e2c);
                    if (s <= thr[p * 4 + r]) {
                        const int idx = atomicAdd(&ncand, 1);
                        if (idx < CAND_CAP) {
                            const int px = p * 16 + quad * 4 + r;
                            cand[idx] = ((unsigned)px << 16) | (unsigned)code;
                        }
                    }
                }
        }
        __syncthreads();
        nc = ncand;
        if (nc > CAND_CAP) nc = CAND_CAP;   // absolute safety
    }

    // ---- rescue: exact fp32 serial ascending-d chain per candidate ----
    for (int i = tid; i < nc; i += 256) {
        const unsigned pc = cand[i];
        const int px = (int)(pc >> 16);
        const int k  = (int)(pc & 0xFFFFu);
        const float* crow = cb + (size_t)k * VQ_D;
        const float* xrow = xl + px * ROWF;
        float dot = 0.f;
        #pragma unroll
        for (int q = 0; q < 32; ++q) {
            const float4 cv = *(const float4*)(crow + q * 4);
            const float4 xv = *(const float4*)(xrow + q * 4);
            dot = fmaf(xv.x, cv.x, dot);
            dot = fmaf(xv.y, cv.y, dot);
            dot = fmaf(xv.z, cv.z, dot);
            dot = fmaf(xv.w, cv.w, dot);
        }
        const float t3 = (x2s[px] - 2.0f * dot) + e2l[k];
        const unsigned long long key =
            ((unsigned long long)__float_as_uint(t3) << 32) | (unsigned)k;
        atomicMin(&fkey[px], key);
    }
    __syncthreads();

    // ---- writeback ----
    {
        const int px = tid & 63;
        const int dh = tid >> 6;
        const int fb = (int)(fkey[px] & 0xFFFFFFFFULL);
        const float* crow = cb + (size_t)fb * VQ_D;
        float* og = out + (size_t)b * VQ_D * VQ_HW + hw0;
        #pragma unroll
        for (int i = 0; i < 32; ++i) {
            const int d = dh * 32 + i;
            og[(size_t)d * VQ_HW + px] = crow[d];
        }
    }
}

extern "C" void kernel_launch(void* const* d_in, const int* in_sizes, int n_in,
                              void* d_out, int out_size, void* d_ws, size_t ws_size,
                              hipStream_t stream) {
    const float* latents = (const float*)d_in[0];
    const float* cb      = (const float*)d_in[1];
    unsigned short* cbbf = (unsigned short*)d_ws;              // 256 KB
    float* e2            = (float*)((char*)d_ws + 262144);     // 4 KB
    float* out           = (float*)d_out;

    vq_prep_kernel<<<dim3(8), dim3(128), 0, stream>>>(cb, cbbf, e2);
    vq_main_kernel<<<dim3(1024), dim3(256), 0, stream>>>(latents, cb, cbbf, e2, out);
}